// Round 9
// baseline (69.981 us; speedup 1.0000x reference)
//
#include <hip/hip_runtime.h>
#include <math.h>

constexpr int BGR = 1024;
constexpr int NN  = 128;
constexpr int EG  = 2048;
constexpr int FIN = 30;
constexpr int H1  = 30;
constexpr int H2  = 50;
constexpr int K1  = 103;
constexpr int K2  = 83;
constexpr int FCW = 100;
constexpr int NT  = 512;
constexpr int EPT = EG/NT;        // 4 packed edges/thread
constexpr int EGP = EG + NN*4;    // padded CSR (deg rounded to x4)

// XB: node rows of 32 floats, chunk-rotated swizzle:
//   feature i of row n -> dword n*32 + (((i>>2)+n)&7)*4 + (i&3)
// XB is time-shared: x -> agg1 -> h1-gated -> agg2 (barrier-separated).
constexpr int XBSZ = NN*32;       // 16384 B

__device__ __forceinline__ void row_fma2(int s, float w, const float* XB, int cq,
                                         float4& a0, float4& a1)
{
  int base=s<<5, rot=s&7;
  float4 v0=*(const float4*)&XB[base+(((cq  +rot)&7)<<2)];
  float4 v1=*(const float4*)&XB[base+(((cq+1+rot)&7)<<2)];
  a0.x=fmaf(w,v0.x,a0.x); a0.y=fmaf(w,v0.y,a0.y); a0.z=fmaf(w,v0.z,a0.z); a0.w=fmaf(w,v0.w,a0.w);
  a1.x=fmaf(w,v1.x,a1.x); a1.y=fmaf(w,v1.y,a1.y); a1.z=fmaf(w,v1.z,a1.z); a1.w=fmaf(w,v1.w,a1.w);
}

// mm over own XB row (streamed, 8 x b128), weights scalar from global.
// CNT outputs at column base qtu*QW. Also computes pool dot vs pvec.
#define MM_BODY(CNT, QW, HTOT, Wp, bp, pvec, hout, dout) {                     \
  const float* Wq=(Wp)+qtu*(QW); const float* bq=(bp)+qtu*(QW);                \
  const float* pq=(pvec)+qtu*(QW);                                            \
  _Pragma("unroll") for (int jo=0;jo<(CNT);jo++) hout[jo]=bq[jo];             \
  _Pragma("unroll") for (int c=0;c<8;c++){                                    \
    float4 a=*(const float4*)&XB[(nG<<5)+(((c+(nG&7))&7)<<2)];                \
    _Pragma("unroll") for (int e=0;e<4;e++) if (c*4+e<FIN){                   \
      float ai=(e==0)?a.x:(e==1)?a.y:(e==2)?a.z:a.w;                          \
      const float* wr=Wq+(c*4+e)*(HTOT);                                      \
      _Pragma("unroll") for (int jo=0;jo<(CNT);jo++)                          \
        hout[jo]=fmaf(ai,wr[jo],hout[jo]);                                    \
    } }                                                                       \
  dout=0.f;                                                                   \
  _Pragma("unroll") for (int jo=0;jo<(CNT);jo++){                             \
    hout[jo]=fmaxf(hout[jo],0.f); dout += hout[jo]*pq[jo]; }                  \
}

__global__ __launch_bounds__(NT, 8) void gnn_fused(
    const float* __restrict__ x, const int* __restrict__ ei,
    const float* __restrict__ W1, const float* __restrict__ b1, const float* __restrict__ p1,
    const float* __restrict__ W2, const float* __restrict__ b2, const float* __restrict__ p2,
    const float* __restrict__ fc1W, const float* __restrict__ fc1b,
    const float* __restrict__ fc2W, const float* __restrict__ fc2b,
    float* __restrict__ out)
{
  const int g = blockIdx.x, tid = threadIdx.x;
  const int lane = tid&63;
  const int wv   = tid>>6;                  // wave 0..7
  const int qt   = wv&3;                    // wave-uniform feature quarter
  const int nG   = (tid>>8)*64 + lane;      // node: waves 0-3 -> 0..63, 4-7 -> 64..127
  const int qtu  = __builtin_amdgcn_readfirstlane(qt);

  __shared__ float XB[XBSZ];
  __shared__ unsigned char eord[EGP];
  __shared__ int   cur[NN];
  __shared__ short cstart[NN];
  __shared__ float dsc[NN];                 // dinv <-> score (barrier-guarded)
  __shared__ signed char rmap[NN];
  __shared__ float sd[4*NN];                // per-quarter partial pool dots
  __shared__ float pmx[8*13], psm[8*13], pol[2*H2], zfc[FCW];
  __shared__ int sh_wtot;

  // ---- packed edges in registers: src | dst<<8 ----
  int epk[EPT];
  {
    const int* srcg = ei + (size_t)g*EG;
    const int* dstg = ei + (size_t)BGR*EG + (size_t)g*EG;
    #pragma unroll
    for (int j=0;j<EPT;j++){ int e=tid+j*NT; epk[j]=(srcg[e]&127)|((dstg[e]&127)<<8); }
  }
  // ---- stage x into swizzled XB; zero chunk-7 tail dwords (feats 30,31) ----
  for (int l2=tid; l2<NN*15; l2+=NT){
    int n=l2/15, i=(l2-n*15)*2;
    float2 v=*(const float2*)&x[(size_t)g*NN*FIN + n*FIN + i];
    *(float2*)&XB[(n<<5) + ((((i>>2)+n)&7)<<2) + (i&3)] = v;
  }
  if (tid<NN){
    int o=(tid<<5)+((((7)+tid)&7)<<2);
    XB[o+2]=0.f; XB[o+3]=0.f;
    cur[tid]=0;
  }
  __syncthreads();

  // ================= CSR build 1 =================
  #pragma unroll
  for (int j=0;j<EPT;j++) atomicAdd(&cur[epk[j]>>8],1);
  __syncthreads();
  {
    int mydeg=(tid<NN)?cur[tid]:0;
    int mydeg4=(mydeg+3)&~3;
    int v=mydeg4;
    #pragma unroll
    for (int off=1;off<64;off<<=1){ int t=__shfl_up(v,off,64); if (lane>=off) v+=t; }
    if (tid==63) sh_wtot=v;
    for (int l=tid;l<EGP/4;l+=NT) ((int*)eord)[l]=-1;     // holes = 0xFF
    __syncthreads();
    int start=v-mydeg4+((tid>=64)?sh_wtot:0);
    if (tid<NN){ cur[tid]=start; cstart[tid]=(short)start; dsc[tid]=1.0f/sqrtf((float)mydeg+1.0f); }
  }
  __syncthreads();
  #pragma unroll
  for (int j=0;j<EPT;j++){ int p=atomicAdd(&cur[epk[j]>>8],1); eord[p]=(unsigned char)(epk[j]&255); }
  __syncthreads();

  // ================= gather1: agg1 = A~ * x (quarter-mapped) =================
  float4 ga0={0,0,0,0}, ga1={0,0,0,0};
  {
    const int cq=qt<<1;
    int e0=cstart[nG], deg=cur[nG]-e0;
    float di=dsc[nG];
    int kend=e0+((deg+3)&~3);
    for (int k=e0;k<kend;k+=4){
      uchar4 ss=*(const uchar4*)&eord[k];
      float w0=(ss.x<128)? di*dsc[ss.x&127] : 0.f;
      float w1=(ss.y<128)? di*dsc[ss.y&127] : 0.f;
      float w2=(ss.z<128)? di*dsc[ss.z&127] : 0.f;
      float w3=(ss.w<128)? di*dsc[ss.w&127] : 0.f;
      row_fma2(ss.x&127,w0,XB,cq,ga0,ga1);
      row_fma2(ss.y&127,w1,XB,cq,ga0,ga1);
      row_fma2(ss.z&127,w2,XB,cq,ga0,ga1);
      row_fma2(ss.w&127,w3,XB,cq,ga0,ga1);
    }
    row_fma2(nG, 1.0f/((float)deg+1.0f), XB, cq, ga0,ga1);   // self loop
  }
  __syncthreads();                 // all XB(x) reads done
  {  // write agg1 into own XB row (chunks cq,cq+1, same swizzle)
    const int cq=qt<<1;
    int base=nG<<5, rot=nG&7;
    *(float4*)&XB[base+(((cq+rot)&7)<<2)]=ga0;
    if (qt<3) *(float4*)&XB[base+(((cq+1+rot)&7)<<2)]=ga1;
    else      *(float2*)&XB[base+(((cq+1+rot)&7)<<2)]=make_float2(ga1.x,ga1.y);
  }
  __syncthreads();                 // agg1 ready

  // ================= mm1 (scalar-W, streamed A) + pool1 partial ==============
  float h[8]={0,0,0,0,0,0,0,0};
  {
    float dd;
    if (qtu<3) MM_BODY(8,8,H1,W1,b1,p1,h,dd)
    else       MM_BODY(6,8,H1,W1,b1,p1,h,dd)
    sd[qt*NN+nG]=dd;
  }
  __syncthreads();
  if (tid<NN){
    float nr=0.f;
    #pragma unroll
    for (int i=0;i<H1;i++){ float pv=p1[i]; nr+=pv*pv; }
    float dt=sd[tid]+sd[NN+tid]+sd[2*NN+tid]+sd[3*NN+tid];
    dsc[tid]=tanhf(dt/sqrtf(nr));
  }
  __syncthreads();
  {  // stable rank (4-way split) == jax.lax.top_k order
    int nR=tid>>2, sub=tid&3;
    float si=dsc[nR];
    int m0=sub<<5, r=0;
    for (int m=m0;m<m0+32;m++){ float sm=dsc[m]; r += (sm>si)||(sm==si&&m<nR); }
    r += __shfl_xor(r,1,64); r += __shfl_xor(r,2,64);
    if (sub==0) rmap[nR]=(r<K1)?(signed char)r:(signed char)-1;
  }
  __syncthreads();
  {  // gated compact -> swizzled XB rows by rank
    int r=rmap[nG];
    if (r>=0){
      float gv=dsc[nG];
      if (qtu<3){
        #pragma unroll
        for (int j=0;j<8;j++){ int i=qtu*8+j; XB[(r<<5)+((((i>>2)+r)&7)<<2)+(i&3)]=h[j]*gv; }
      } else {
        #pragma unroll
        for (int j=0;j<6;j++){ int i=24+j; XB[(r<<5)+((((i>>2)+r)&7)<<2)+(i&3)]=h[j]*gv; }
      }
    }
  }
  #pragma unroll
  for (int j=0;j<EPT;j++){
    int ns=rmap[epk[j]&255], nd=rmap[epk[j]>>8];
    epk[j]=((ns|nd)<0)? -1 : (ns|(nd<<8));
  }
  if (tid<K1) cur[tid]=0;
  __syncthreads();

  // ================= CSR build 2 =================
  #pragma unroll
  for (int j=0;j<EPT;j++) if (epk[j]>=0) atomicAdd(&cur[epk[j]>>8],1);
  __syncthreads();
  {
    int mydeg=(tid<K1)?cur[tid]:0;
    int mydeg4=(mydeg+3)&~3;
    int v=mydeg4;
    #pragma unroll
    for (int off=1;off<64;off<<=1){ int t=__shfl_up(v,off,64); if (lane>=off) v+=t; }
    if (tid==63) sh_wtot=v;
    for (int l=tid;l<EGP/4;l+=NT) ((int*)eord)[l]=-1;
    __syncthreads();
    int start=v-mydeg4+((tid>=64)?sh_wtot:0);
    if (tid<K1){ cur[tid]=start; cstart[tid]=(short)start; dsc[tid]=1.0f/sqrtf((float)mydeg+1.0f); }
  }
  __syncthreads();
  #pragma unroll
  for (int j=0;j<EPT;j++) if (epk[j]>=0){ int p=atomicAdd(&cur[epk[j]>>8],1); eord[p]=(unsigned char)(epk[j]&255); }
  __syncthreads();

  // ================= gather2: agg2 = A2~ * h1g ===============================
  ga0=(float4){0,0,0,0}; ga1=(float4){0,0,0,0};
  if (nG<K1){
    const int cq=qt<<1;
    int e0=cstart[nG], deg=cur[nG]-e0;
    float di=dsc[nG];
    int kend=e0+((deg+3)&~3);
    for (int k=e0;k<kend;k+=4){
      uchar4 ss=*(const uchar4*)&eord[k];
      float w0=(ss.x<128)? di*dsc[ss.x&127] : 0.f;
      float w1=(ss.y<128)? di*dsc[ss.y&127] : 0.f;
      float w2=(ss.z<128)? di*dsc[ss.z&127] : 0.f;
      float w3=(ss.w<128)? di*dsc[ss.w&127] : 0.f;
      row_fma2(ss.x&127,w0,XB,cq,ga0,ga1);
      row_fma2(ss.y&127,w1,XB,cq,ga0,ga1);
      row_fma2(ss.z&127,w2,XB,cq,ga0,ga1);
      row_fma2(ss.w&127,w3,XB,cq,ga0,ga1);
    }
    row_fma2(nG, 1.0f/((float)deg+1.0f), XB, cq, ga0,ga1);
  }
  __syncthreads();                 // all XB(h1g) reads done
  if (nG<K1){
    const int cq=qt<<1;
    int base=nG<<5, rot=nG&7;
    *(float4*)&XB[base+(((cq+rot)&7)<<2)]=ga0;
    if (qt<3) *(float4*)&XB[base+(((cq+1+rot)&7)<<2)]=ga1;
    else      *(float2*)&XB[base+(((cq+1+rot)&7)<<2)]=make_float2(ga1.x,ga1.y);
  }
  __syncthreads();                 // agg2 ready

  // ================= mm2 (scalar-W, streamed A) + pool2 partial ==============
  float oc[13]={0,0,0,0,0,0,0,0,0,0,0,0,0};
  if (nG<K1){
    float dd;
    if (qtu<3) MM_BODY(13,13,H2,W2,b2,p2,oc,dd)
    else       MM_BODY(11,13,H2,W2,b2,p2,oc,dd)
    sd[qt*NN+nG]=dd;
  }
  __syncthreads();
  if (tid<K1){
    float nr=0.f;
    #pragma unroll
    for (int i=0;i<H2;i++){ float pv=p2[i]; nr+=pv*pv; }
    float dt=sd[tid]+sd[NN+tid]+sd[2*NN+tid]+sd[3*NN+tid];
    dsc[tid]=tanhf(dt/sqrtf(nr));
  }
  __syncthreads();
  {  // rank2 (4-way split, keep flag)
    int nR=tid>>2, sub=tid&3;
    float si=(nR<K1)?dsc[nR]:0.f;
    int m0=sub*26, m1=m0+26; if (m1>K1) m1=K1;
    int r=0;
    for (int m=m0;m<m1;m++){ float sm=dsc[m]; r += (sm>si)||(sm==si&&m<nR); }
    r += __shfl_xor(r,1,64); r += __shfl_xor(r,2,64);
    if (sub==0 && nR<K1) rmap[nR]=(r<K2)?(signed char)1:(signed char)-1;
  }
  __syncthreads();

  // ================= gated global max/mean ===================================
  {
    bool kept=(nG<K1)&&(rmap[nG]>0);
    float gv=kept?dsc[nG]:0.f;
    float mx[13],sm[13];
    #pragma unroll
    for (int j=0;j<13;j++){ float v=oc[j]*gv; sm[j]=kept?v:0.f; mx[j]=kept?v:-3.4e38f; }
    #pragma unroll
    for (int off=1;off<64;off<<=1){
      #pragma unroll
      for (int j=0;j<13;j++){ mx[j]=fmaxf(mx[j],__shfl_xor(mx[j],off,64)); sm[j]+=__shfl_xor(sm[j],off,64); }
    }
    if (lane==0){
      #pragma unroll
      for (int j=0;j<13;j++){ pmx[wv*13+j]=mx[j]; psm[wv*13+j]=sm[j]; }
    }
  }
  __syncthreads();
  if (tid<H2){
    int q=tid/13, j=tid-q*13;
    float m=fmaxf(pmx[q*13+j], pmx[(q+4)*13+j]);
    float s=psm[q*13+j]+psm[(q+4)*13+j];
    pol[tid]=m;
    pol[H2+tid]=s*(1.0f/(float)K2);
  }
  __syncthreads();

  // ================= fc1 + fc2 =================
  if (tid<FCW){
    float acc=fc1b[tid];
    #pragma unroll 4
    for (int i=0;i<2*H2;i++) acc += pol[i]*fc1W[i*FCW+tid];
    zfc[tid]=fmaxf(acc,0.f);
  }
  __syncthreads();
  if (tid<64){
    float a=0.f;
    for (int j=tid;j<FCW;j+=64) a += zfc[j]*fc2W[j];
    #pragma unroll
    for (int off=32;off;off>>=1) a += __shfl_down(a,off,64);
    if (tid==0){
      float acc=fc2b[0]+a;
      out[g]=1.0f/(1.0f+expf(-acc));
    }
  }
}

extern "C" void kernel_launch(void* const* d_in, const int* in_sizes, int n_in,
                              void* d_out, int out_size, void* d_ws, size_t ws_size,
                              hipStream_t stream) {
  const float* x    = (const float*)d_in[0];
  const int*   ei   = (const int*)d_in[1];
  // d_in[2] = batch (unused; graphs are equal-size, contiguous)
  const float* W1   = (const float*)d_in[3];
  const float* b1   = (const float*)d_in[4];
  const float* p1   = (const float*)d_in[5];
  const float* W2   = (const float*)d_in[6];
  const float* b2   = (const float*)d_in[7];
  const float* p2   = (const float*)d_in[8];
  const float* fc1W = (const float*)d_in[9];
  const float* fc1b = (const float*)d_in[10];
  const float* fc2W = (const float*)d_in[11];
  const float* fc2b = (const float*)d_in[12];
  float* outp = (float*)d_out;

  gnn_fused<<<BGR, NT, 0, stream>>>(x, ei, W1, b1, p1, W2, b2, p2,
                                    fc1W, fc1b, fc2W, fc2b, outp);
}